// Round 9
// baseline (6138.234 us; speedup 1.0000x reference)
//
#include <hip/hip_runtime.h>
#include <hip/hip_bf16.h>
#include <stdint.h>

#define B_SZ 2048
#define H_SZ 1024
#define S_SZ 128
#define G4   4096
#define BK   64
#define NKK  16            // K phases per step
#define BM   128
#define BN   256
#define NJT  16            // G4/BN
#define NBLK 256

typedef short short8 __attribute__((ext_vector_type(8)));
typedef float floatx4 __attribute__((ext_vector_type(4)));

#define AS1 __attribute__((address_space(1)))
#define AS3 __attribute__((address_space(3)))

// Persistent device buffers (fully rewritten/reset on every kernel_launch).
// W and h storage is XOR-swizzled within each 128B row-chunk
// (stored elem = k ^ ((row&7)<<3)) -- r2-proven: linear global_load_lds
// staging + the same XOR on ds_read = zero bank conflicts.
__device__ ushort g_Wp[G4 * H_SZ];       // packed W_hh bf16: row j=(h/16)*64+gate*16+(h%16)
__device__ ushort g_h[2][B_SZ * H_SZ];   // hidden bf16 ping-pong
__device__ float  g_wih[G4];             // packed W_ih
__device__ float  g_bias[G4];            // packed b_ih + b_hh
__device__ float  g_pp[2][B_SZ][NJT];    // pred partials [t&1][row][jt]
__device__ unsigned g_bar[8 * 32];       // per-XCD arrive counters (128B apart)
__device__ unsigned g_sense[8 * 32];     // per-XCD generation

__device__ __forceinline__ ushort f2bf(float f) {
  unsigned u = __float_as_uint(f);
  return (ushort)((u + 0x7FFFu + ((u >> 16) & 1u)) >> 16);
}
__device__ __forceinline__ float fsig(float x) { return 1.f / (1.f + __expf(-x)); }
__device__ __forceinline__ float ftanh(float x) { return 1.f - 2.f / (__expf(2.f * x) + 1.f); }

__device__ __forceinline__ void gload16(const void* g, void* l) {
  __builtin_amdgcn_global_load_lds((const AS1 void*)g, (AS3 void*)l, 16, 0, 0);
}

// Per-XCD barrier: 32 blocks of one XCD share an L2; all recurrence data is
// XCD-local by construction. Full agent release/acquire fences (r6-proven
// pattern) guarantee visibility of h / g_pp written by XCD-mates.
__device__ __forceinline__ void xcd_barrier(int grp) {
  __syncthreads();
  if (threadIdx.x == 0) {
    __builtin_amdgcn_fence(__ATOMIC_RELEASE, "agent");
    unsigned gen = __hip_atomic_load(&g_sense[grp * 32], __ATOMIC_RELAXED,
                                     __HIP_MEMORY_SCOPE_AGENT);
    unsigned a = __hip_atomic_fetch_add(&g_bar[grp * 32], 1u, __ATOMIC_RELAXED,
                                        __HIP_MEMORY_SCOPE_AGENT);
    if (a == 31u) {
      __hip_atomic_store(&g_bar[grp * 32], 0u, __ATOMIC_RELAXED, __HIP_MEMORY_SCOPE_AGENT);
      __hip_atomic_store(&g_sense[grp * 32], gen + 1u, __ATOMIC_RELAXED,
                         __HIP_MEMORY_SCOPE_AGENT);
    } else {
      while (__hip_atomic_load(&g_sense[grp * 32], __ATOMIC_RELAXED,
                               __HIP_MEMORY_SCOPE_AGENT) == gen)
        __builtin_amdgcn_s_sleep(2);
    }
    __builtin_amdgcn_fence(__ATOMIC_ACQUIRE, "agent");
  }
  __syncthreads();
}

// ---------------- prep kernels ----------------

__global__ __launch_bounds__(256) void prep_wpack(const float* __restrict__ Whh) {
  const int gid = blockIdx.x * 256 + threadIdx.x;  // 524288
  const int j   = gid >> 7;                        // packed row 0..4095
  const int k8  = (gid & 127) << 3;                // k offset
  const int gate = (j >> 4) & 3;
  const int h    = ((j >> 6) << 4) | (j & 15);
  const float* src = Whh + (size_t)(gate * H_SZ + h) * H_SZ + k8;
  floatx4 a = *(const floatx4*)src;
  floatx4 b = *(const floatx4*)(src + 4);
  short8 o;
#pragma unroll
  for (int i = 0; i < 4; ++i) o[i] = (short)f2bf(a[i]);
#pragma unroll
  for (int i = 0; i < 4; ++i) o[4 + i] = (short)f2bf(b[i]);
  *(short8*)&g_Wp[(size_t)j * H_SZ + (k8 ^ ((j & 7) << 3))] = o;
}

__global__ __launch_bounds__(256) void prep_misc(const float* __restrict__ Wih,
                                                 const float* __restrict__ bih,
                                                 const float* __restrict__ bhh) {
  if (blockIdx.x == 0) {  // reset barrier state every call (determinism)
    if (threadIdx.x < 8) {
      g_bar[threadIdx.x * 32]   = 0u;
      g_sense[threadIdx.x * 32] = 0u;
    }
  }
  const int j = blockIdx.x * 256 + threadIdx.x;  // 4096
  const int gate = (j >> 4) & 3;
  const int h    = ((j >> 6) << 4) | (j & 15);
  const int jp   = gate * H_SZ + h;
  g_wih[j]  = Wih[jp];
  g_bias[j] = bih[jp] + bhh[jp];
}

__global__ __launch_bounds__(256) void prep_h(const float* __restrict__ hidden) {
  const int gid = blockIdx.x * 256 + threadIdx.x;  // 262144
  const int row = gid >> 7;
  const int k8  = (gid & 127) << 3;
  const size_t src = (size_t)row * H_SZ + k8;
  short8 o;
#pragma unroll
  for (int i = 0; i < 8; ++i) o[i] = (short)f2bf(hidden[src + i]);
  *(short8*)&g_h[0][(size_t)row * H_SZ + (k8 ^ ((row & 7) << 3))] = o;
}

// ---------------- persistent all-steps kernel ----------------
// 256 blocks x 512 threads (1 block/CU by LDS). XCD g = bid&7 owns batch
// rows [g*256, g*256+256) and computes ALL 4096 gate-cols for them:
// 32 blocks/XCD = 16 jt x 2 bt. The entire recurrence (h, c, pred, x) is
// XCD-local -> per-XCD barrier only, W/h served by the XCD's own L2.
// K-loop: ring-3 LDS, depth-2 prefetch, counted vmcnt (r7 phase structure).
__global__ __launch_bounds__(512, 1)
void lstm_persistent(const float* __restrict__ cell,
                     const float* __restrict__ Wfc,
                     const float* __restrict__ bfc,
                     float* __restrict__ out) {
  __shared__ ushort Al[3][BM * BK];   // 3 x 16KB
  __shared__ ushort Bl[3][BN * BK];   // 3 x 32KB   (total 144KB)
  __shared__ float  xbuf[BM];
  __shared__ float  predp[4 * BM];

  const int tid  = threadIdx.x;
  const int lane = tid & 63;
  const int wid  = tid >> 6;                  // 0..7
  const int bid  = blockIdx.x;
  const int grp  = bid & 7;                   // XCD (hw round-robin)
  const int idx  = bid >> 3;                  // 0..31 within XCD
  const int jt   = idx >> 1;                  // 0..15
  const int bt   = idx & 1;                   // 0..1
  const int brow = grp * 256 + bt * BM;       // XCD-local batch rows
  const int jcol = jt * BN;
  const int wr = wid >> 2, wc = wid & 3;      // wave tile 2 x 4 (64x64 each)
  const int lr = lane & 15, lk = lane >> 4;

  // staging: linear copy of (swizzled) storage; wave-linear LDS dest.
  const int srow = wid * 8 + (lane >> 3);     // 0..63
  const int scol = (lane & 7) << 3;
  const size_t asrc = (size_t)(brow + srow) * H_SZ + scol;
  const size_t bsrc = (size_t)(jcol + srow) * H_SZ + scol;
  const int dst = srow * BK + scol;           // elem; = wid*512 + lane*8

  int arow[4], brw[4], cxor[2];
#pragma unroll
  for (int m = 0; m < 4; ++m) arow[m] = (wr * 64 + m * 16 + lr) * BK;
#pragma unroll
  for (int n = 0; n < 4; ++n) brw[n] = (wc * 64 + n * 16 + lr) * BK;
  cxor[0] = (lk * 8) ^ ((lr & 7) << 3);
  cxor[1] = (32 + lk * 8) ^ ((lr & 7) << 3);

  // hoisted epilogue constants
  const int hcol = (jt * 4 + wc) * 16 + lr;   // global h index 0..1023
  float wih[4], bb[4];
#pragma unroll
  for (int n = 0; n < 4; ++n) {
    const int col = jcol + wc * 64 + n * 16 + lr;
    wih[n] = g_wih[col];
    bb[n]  = g_bias[col];
  }

  // cell state in registers for the whole sequence
  float creg[4][4];
#pragma unroll
  for (int m = 0; m < 4; ++m)
#pragma unroll
    for (int r = 0; r < 4; ++r) {
      const int row_l = wr * 64 + m * 16 + lk * 4 + r;
      creg[m][r] = cell[(size_t)(brow + row_l) * H_SZ + hcol];
    }

#define STAGE(BUF, KO)                                                      \
  {                                                                         \
    const int ko_ = (KO) * BK;                                              \
    gload16(hin + asrc + ko_, &Al[BUF][dst]);                               \
    gload16(hin + asrc + (size_t)64 * H_SZ + ko_, &Al[BUF][64 * BK + dst]); \
    gload16(g_Wp + bsrc + ko_, &Bl[BUF][dst]);                              \
    gload16(g_Wp + bsrc + (size_t)64 * H_SZ + ko_, &Bl[BUF][64 * BK + dst]);\
    gload16(g_Wp + bsrc + (size_t)128 * H_SZ + ko_, &Bl[BUF][128 * BK + dst]);\
    gload16(g_Wp + bsrc + (size_t)192 * H_SZ + ko_, &Bl[BUF][192 * BK + dst]);\
  }

#define COMPUTE(BUF)                                                        \
  {                                                                         \
    _Pragma("unroll") for (int k2 = 0; k2 < 2; ++k2) {                      \
      short8 a[4], b[4];                                                    \
      _Pragma("unroll") for (int m = 0; m < 4; ++m)                         \
          a[m] = *(const short8*)&Al[BUF][arow[m] + cxor[k2]];              \
      _Pragma("unroll") for (int n = 0; n < 4; ++n)                         \
          b[n] = *(const short8*)&Bl[BUF][brw[n] + cxor[k2]];               \
      __builtin_amdgcn_s_setprio(1);                                        \
      _Pragma("unroll") for (int m = 0; m < 4; ++m)                         \
          _Pragma("unroll") for (int n = 0; n < 4; ++n)                     \
              acc[m][n] = __builtin_amdgcn_mfma_f32_16x16x32_bf16(          \
                  a[m], b[n], acc[m][n], 0, 0, 0);                          \
      __builtin_amdgcn_s_setprio(0);                                        \
    }                                                                       \
  }

// Phase I: drain tile-I loads (leave newer in flight), barrier publishes
// tile I AND guarantees all waves' tile-(I-1) LDS reads are complete
// (their MFMAs consumed them before arriving) -> safe to overwrite
// buf (I+2)%3 == buf (I-1)%3 with the tile-(I+2) prefetch.
#define PHASE(I, VN)                                                        \
  {                                                                         \
    asm volatile("s_waitcnt vmcnt(" #VN ")" ::: "memory");                  \
    __builtin_amdgcn_sched_barrier(0);                                      \
    __builtin_amdgcn_s_barrier();                                           \
    if ((I) + 2 < NKK) { STAGE(((I) + 2) % 3, (I) + 2); }                   \
    COMPUTE((I) % 3);                                                       \
  }

  for (int t = 0; t < S_SZ; ++t) {
    const int p = t & 1;
    const ushort* __restrict__ hin = g_h[p];
    ushort* __restrict__ hout      = g_h[p ^ 1];

    floatx4 acc[4][4];
#pragma unroll
    for (int m = 0; m < 4; ++m)
#pragma unroll
      for (int n = 0; n < 4; ++n) acc[m][n] = {0.f, 0.f, 0.f, 0.f};

    // prologue: depth-2 prefetch (12 loads/thread in flight)
    STAGE(0, 0);
    STAGE(1, 1);

    PHASE(0, 6);  PHASE(1, 6);  PHASE(2, 6);  PHASE(3, 6);
    PHASE(4, 6);  PHASE(5, 6);  PHASE(6, 6);  PHASE(7, 6);
    PHASE(8, 6);  PHASE(9, 6);  PHASE(10, 6); PHASE(11, 6);
    PHASE(12, 6); PHASE(13, 6); PHASE(14, 6); PHASE(15, 0);

    // ---------------- epilogue ----------------
    if (t > 0 && tid < BM) {
      float s = bfc[t - 1];
      const float* pr = &g_pp[(t - 1) & 1][brow + tid][0];
#pragma unroll
      for (int j = 0; j < 4; ++j) {
        floatx4 v = *(const floatx4*)&pr[j * 4];
        s += v[0] + v[1] + v[2] + v[3];
      }
      xbuf[tid] = s;
      if (jt == 0) out[(size_t)(brow + tid) * S_SZ + (t - 1)] = s;
    }
    __syncthreads();

    const float wfc_l = Wfc[(size_t)t * H_SZ + hcol];  // own-step head weight

#pragma unroll
    for (int m = 0; m < 4; ++m) {
#pragma unroll
      for (int r = 0; r < 4; ++r) {
        const int row_l = wr * 64 + m * 16 + lk * 4 + r;
        const float xv = (t > 0) ? xbuf[row_l] : 0.f;
        float gi = acc[m][0][r] + xv * wih[0] + bb[0];
        float gf = acc[m][1][r] + xv * wih[1] + bb[1];
        float gg = acc[m][2][r] + xv * wih[2] + bb[2];
        float go = acc[m][3][r] + xv * wih[3] + bb[3];
        float cn = fsig(gf) * creg[m][r] + fsig(gi) * ftanh(gg);
        creg[m][r] = cn;
        float hv = fsig(go) * ftanh(cn);
        // swizzled h store (storage row = brow+row_l; (brow+row_l)&7 == row_l&7)
        hout[(size_t)(brow + row_l) * H_SZ + (hcol ^ ((row_l & 7) << 3))] = f2bf(hv);
        // own-step head partial: pred_t[row] += h_t[row,hcol]*Wfc[t,hcol]
        float pp = hv * wfc_l;
        pp += __shfl_xor(pp, 1);
        pp += __shfl_xor(pp, 2);
        pp += __shfl_xor(pp, 4);
        pp += __shfl_xor(pp, 8);
        if (lr == 0) predp[wc * BM + row_l] = pp;
      }
    }
    __syncthreads();
    if (tid < BM)
      g_pp[p][brow + tid][jt] = predp[tid] + predp[BM + tid] +
                                predp[2 * BM + tid] + predp[3 * BM + tid];

    xcd_barrier(grp);
  }

  // final head output for t = S-1 (127 odd -> partials in g_pp[1])
  if (jt == 0 && tid < BM) {
    float s = bfc[S_SZ - 1];
    const float* pr = &g_pp[1][brow + tid][0];
#pragma unroll
    for (int j = 0; j < 4; ++j) {
      floatx4 v = *(const floatx4*)&pr[j * 4];
      s += v[0] + v[1] + v[2] + v[3];
    }
    out[(size_t)(brow + tid) * S_SZ + (S_SZ - 1)] = s;
  }
#undef STAGE
#undef COMPUTE
#undef PHASE
}

extern "C" void kernel_launch(void* const* d_in, const int* in_sizes, int n_in,
                              void* d_out, int out_size, void* d_ws, size_t ws_size,
                              hipStream_t stream) {
  const float* hidden = (const float*)d_in[0];
  const float* cell   = (const float*)d_in[1];
  const float* W_ih   = (const float*)d_in[2];
  const float* W_hh   = (const float*)d_in[3];
  const float* b_ih   = (const float*)d_in[4];
  const float* b_hh   = (const float*)d_in[5];
  const float* W_fc   = (const float*)d_in[6];
  const float* b_fc   = (const float*)d_in[7];
  float* out = (float*)d_out;

  prep_wpack<<<2048, 256, 0, stream>>>(W_hh);
  prep_misc<<<16, 256, 0, stream>>>(W_ih, b_ih, b_hh);
  prep_h<<<1024, 256, 0, stream>>>(hidden);

  lstm_persistent<<<NBLK, 512, 0, stream>>>(cell, W_fc, b_fc, out);
}

// Round 11
// 5789.021 us; speedup vs baseline: 1.0603x; 1.0603x over previous
//
#include <hip/hip_runtime.h>
#include <hip/hip_bf16.h>
#include <stdint.h>

#define B_SZ 2048
#define H_SZ 1024
#define S_SZ 128
#define G4   4096
#define BK   64
#define NKK  16            // K phases per step
#define BM   128
#define BN   256
#define NJT  16            // G4/BN
#define NBLK 256

typedef short short8 __attribute__((ext_vector_type(8)));
typedef int   intx4  __attribute__((ext_vector_type(4)));
typedef float floatx4 __attribute__((ext_vector_type(4)));

#define AS1 __attribute__((address_space(1)))
#define AS3 __attribute__((address_space(3)))

// Persistent device buffers (fully rewritten/reset on every kernel_launch).
// g_Wp: row-swizzled storage (elem = k ^ ((row&7)<<3)); linear global_load_lds
// staging + XOR'd ds_read = zero bank conflicts (r2-proven). W is immutable
// during the persistent kernel -> normal cached reads are safe under the
// release-only barrier and stay L2-warm for all 128 steps.
// g_h: LINEAR. h crosses blocks -> read ONLY via sc0/sc1 bypass loads
// (LLC-coherent; r8-proven replay-stable). Swizzle applied at ds_write time.
// g_pp: crosses blocks -> read ONLY via agent-scope atomic loads (r8-proven).
__device__ ushort g_Wp[G4 * H_SZ];       // packed W_hh bf16: row j=(h/16)*64+gate*16+(h%16)
__device__ ushort g_h[2][B_SZ * H_SZ];   // hidden bf16 ping-pong, linear
__device__ float  g_wih[G4];             // packed W_ih
__device__ float  g_bias[G4];            // packed b_ih + b_hh
__device__ float  g_pp[2][B_SZ][NJT];    // pred partials [t&1][row][jt]
__device__ unsigned g_bar[8 * 32];       // per-group arrive counters (128B apart)
__device__ unsigned g_sense[8 * 32];     // per-group generation

__device__ __forceinline__ ushort f2bf(float f) {
  unsigned u = __float_as_uint(f);
  return (ushort)((u + 0x7FFFu + ((u >> 16) & 1u)) >> 16);
}
__device__ __forceinline__ float fsig(float x) { return 1.f / (1.f + __expf(-x)); }
__device__ __forceinline__ float ftanh(float x) { return 1.f - 2.f / (__expf(2.f * x) + 1.f); }

__device__ __forceinline__ void gload16(const void* g, void* l) {
  __builtin_amdgcn_global_load_lds((const AS1 void*)g, (AS3 void*)l, 16, 0, 0);
}

// RELEASE-ONLY per-group barrier (r8-proven replay-stable): entry
// __syncthreads drains each wave's stores into L2; tid0's release fence
// writes dirty L2 back to LLC before arriving. No invalidate anywhere --
// every cross-block read path bypasses L2 (sc0sc1 / atomics), so stale
// L2 copies can never be consulted. Correct for ANY block->XCD mapping.
__device__ __forceinline__ void grp_barrier(int grp) {
  __syncthreads();
  if (threadIdx.x == 0) {
    __builtin_amdgcn_fence(__ATOMIC_RELEASE, "agent");  // writeback dirty L2
    unsigned gen = __hip_atomic_load(&g_sense[grp * 32], __ATOMIC_RELAXED,
                                     __HIP_MEMORY_SCOPE_AGENT);
    unsigned a = __hip_atomic_fetch_add(&g_bar[grp * 32], 1u, __ATOMIC_RELAXED,
                                        __HIP_MEMORY_SCOPE_AGENT);
    if (a == 31u) {
      __hip_atomic_store(&g_bar[grp * 32], 0u, __ATOMIC_RELAXED, __HIP_MEMORY_SCOPE_AGENT);
      __hip_atomic_store(&g_sense[grp * 32], gen + 1u, __ATOMIC_RELAXED,
                         __HIP_MEMORY_SCOPE_AGENT);
    } else {
      while (__hip_atomic_load(&g_sense[grp * 32], __ATOMIC_RELAXED,
                               __HIP_MEMORY_SCOPE_AGENT) == gen)
        __builtin_amdgcn_s_sleep(2);
    }
    asm volatile("" ::: "memory");
  }
  __syncthreads();
}

// ---------------- prep kernels ----------------

__global__ __launch_bounds__(256) void prep_wpack(const float* __restrict__ Whh) {
  const int gid = blockIdx.x * 256 + threadIdx.x;  // 524288
  const int j   = gid >> 7;                        // packed row 0..4095
  const int k8  = (gid & 127) << 3;                // k offset
  const int gate = (j >> 4) & 3;
  const int h    = ((j >> 6) << 4) | (j & 15);
  const float* src = Whh + (size_t)(gate * H_SZ + h) * H_SZ + k8;
  floatx4 a = *(const floatx4*)src;
  floatx4 b = *(const floatx4*)(src + 4);
  short8 o;
#pragma unroll
  for (int i = 0; i < 4; ++i) o[i] = (short)f2bf(a[i]);
#pragma unroll
  for (int i = 0; i < 4; ++i) o[4 + i] = (short)f2bf(b[i]);
  *(short8*)&g_Wp[(size_t)j * H_SZ + (k8 ^ ((j & 7) << 3))] = o;
}

__global__ __launch_bounds__(256) void prep_misc(const float* __restrict__ Wih,
                                                 const float* __restrict__ bih,
                                                 const float* __restrict__ bhh) {
  if (blockIdx.x == 0) {  // reset barrier state every call (determinism)
    if (threadIdx.x < 8) {
      g_bar[threadIdx.x * 32]   = 0u;
      g_sense[threadIdx.x * 32] = 0u;
    }
  }
  const int j = blockIdx.x * 256 + threadIdx.x;  // 4096
  const int gate = (j >> 4) & 3;
  const int h    = ((j >> 6) << 4) | (j & 15);
  const int jp   = gate * H_SZ + h;
  g_wih[j]  = Wih[jp];
  g_bias[j] = bih[jp] + bhh[jp];
}

__global__ __launch_bounds__(256) void prep_h(const float* __restrict__ hidden) {
  const int gid = blockIdx.x * 256 + threadIdx.x;  // 262144
  const int o8  = gid << 3;
  short8 o;
#pragma unroll
  for (int i = 0; i < 8; ++i) o[i] = (short)f2bf(hidden[o8 + i]);
  *(short8*)&g_h[0][o8] = o;
}

// ---------------- persistent all-steps kernel ----------------
// 256 blocks x 512 threads (1 block/CU). Group g = bid&7 owns batch rows
// [g*256, g*256+256) and all 4096 gate-cols (32 blocks = 16 jt x 2 bt) ->
// the whole recurrence is group-local; per-group barrier suffices.
// K-loop: 16 phases; A (h) reg-staged via sc0sc1 bypass issued 3 phases
// ahead (ring-4 regs) + swizzled ds_write (dbuf-2 LDS); B (W) via
// global_load_lds from swizzled storage (dbuf-2); counted vmcnt.
__global__ __launch_bounds__(512, 1)
void lstm_persistent(const float* __restrict__ cell,
                     const float* __restrict__ Wfc,
                     const float* __restrict__ bfc,
                     float* __restrict__ out) {
  __shared__ ushort Al[2][BM * BK];   // 2 x 16KB
  __shared__ ushort Bl[2][BN * BK];   // 2 x 32KB   (96KB total)
  __shared__ float  xbuf[BM];
  __shared__ float  predp[4 * BM];

  const int tid  = threadIdx.x;
  const int lane = tid & 63;
  const int wid  = tid >> 6;                  // 0..7
  const int bid  = blockIdx.x;
  const int grp  = bid & 7;
  const int idx  = bid >> 3;                  // 0..31 within group
  const int jt   = idx >> 1;                  // 0..15
  const int bt   = idx & 1;                   // 0..1
  const int brow = grp * 256 + bt * BM;       // group-local batch rows
  const int jcol = jt * BN;
  const int wr = wid >> 2, wc = wid & 3;      // wave tile 2 x 4 (64x64 each)
  const int lr = lane & 15, lk = lane >> 4;

  // A staging: thread covers chunks {tid, tid+512}: row = c>>3, col8 = c&7
  const int row0 = tid >> 3, col0 = tid & 7;
  const size_t abase = (size_t)(brow + row0) * H_SZ + (size_t)col0 * 8;
  const int awoff = row0 * BK + ((col0 ^ (row0 & 7)) << 3);
  ushort* const awA = &Al[0][awoff];
  ushort* const awB = &Al[1][awoff];

  // B staging: linear copy of swizzled storage; wave-linear LDS dest
  const int srow = wid * 8 + (lane >> 3);     // 0..63
  const int scol = (lane & 7) << 3;
  const size_t bsrc = (size_t)(jcol + srow) * H_SZ + scol;
  const int bdst = srow * BK + scol;          // = wid*512 + lane*8 (linear)
  ushort* const bdA = &Bl[0][bdst];
  ushort* const bdB = &Bl[1][bdst];

  int arow[4], brw[4], cxor[2];
#pragma unroll
  for (int m = 0; m < 4; ++m) arow[m] = (wr * 64 + m * 16 + lr) * BK;
#pragma unroll
  for (int n = 0; n < 4; ++n) brw[n] = (wc * 64 + n * 16 + lr) * BK;
  cxor[0] = (lk * 8) ^ ((lr & 7) << 3);
  cxor[1] = (32 + lk * 8) ^ ((lr & 7) << 3);

  // hoisted epilogue constants
  const int hcol = (jt * 4 + wc) * 16 + lr;   // global h index 0..1023
  float wih[4], bb[4];
#pragma unroll
  for (int n = 0; n < 4; ++n) {
    const int col = jcol + wc * 64 + n * 16 + lr;
    wih[n] = g_wih[col];
    bb[n]  = g_bias[col];
  }

  // cell state in registers for the whole sequence
  float creg[4][4];
#pragma unroll
  for (int m = 0; m < 4; ++m)
#pragma unroll
    for (int r = 0; r < 4; ++r) {
      const int row_l = wr * 64 + m * 16 + lk * 4 + r;
      creg[m][r] = cell[(size_t)(brow + row_l) * H_SZ + hcol];
    }

  // A reg ring (4 tiles x 2 chunks)
  intx4 A0a, A0b, A1a, A1b, A2a, A2b, A3a, A3b;

#define ISSUE_A(I, QA, QB)                                                  \
  {                                                                         \
    const ushort* as_ = hin + abase + (size_t)(I) * BK;                     \
    asm volatile("global_load_dwordx4 %0, %1, off sc0 sc1"                  \
                 : "=v"(QA) : "v"(as_));                                    \
    asm volatile("global_load_dwordx4 %0, %1, off sc0 sc1"                  \
                 : "=v"(QB) : "v"(as_ + 64 * H_SZ));                        \
  }

#define ISSUE_B(I)                                                          \
  {                                                                         \
    const size_t ko_ = (size_t)(I) * BK;                                    \
    ushort* bd_ = ((I) & 1) ? bdB : bdA;                                    \
    gload16(g_Wp + bsrc + ko_, bd_);                                        \
    gload16(g_Wp + bsrc + (size_t)64 * H_SZ + ko_, bd_ + 64 * BK);          \
    gload16(g_Wp + bsrc + (size_t)128 * H_SZ + ko_, bd_ + 128 * BK);        \
    gload16(g_Wp + bsrc + (size_t)192 * H_SZ + ko_, bd_ + 192 * BK);        \
  }

#define COMPUTE(BUF)                                                        \
  {                                                                         \
    _Pragma("unroll") for (int k2 = 0; k2 < 2; ++k2) {                      \
      short8 a[4], b[4];                                                    \
      _Pragma("unroll") for (int m = 0; m < 4; ++m)                         \
          a[m] = *(const short8*)&Al[BUF][arow[m] + cxor[k2]];              \
      _Pragma("unroll") for (int n = 0; n < 4; ++n)                         \
          b[n] = *(const short8*)&Bl[BUF][brw[n] + cxor[k2]];               \
      __builtin_amdgcn_s_setprio(1);                                        \
      _Pragma("unroll") for (int m = 0; m < 4; ++m)                         \
          _Pragma("unroll") for (int n = 0; n < 4; ++n)                     \
              acc[m][n] = __builtin_amdgcn_mfma_f32_16x16x32_bf16(          \
                  a[m], b[n], acc[m][n], 0, 0, 0);                          \
      __builtin_amdgcn_s_setprio(0);                                        \
    }                                                                       \
  }

// Phase I: issue A(I+3) (3 phases early: ~3700cyc >> HBM latency) and
// B(I+1); counted vmcnt drains tile I's loads (A to regs, B to LDS);
// swizzled ds_write of A(I); barrier publishes; compute tile I.
// WAR on LDS dbufs is protected by the barrier (all waves' tile I-1
// reads completed before they arrive).
#define PH(I, VN, WA, WB, RA, RB)                                           \
  {                                                                         \
    if ((I) + 3 < NKK) { ISSUE_A((I) + 3, WA, WB); }                        \
    if ((I) + 1 < NKK) { ISSUE_B((I) + 1); }                                \
    asm volatile("s_waitcnt vmcnt(" #VN ")" ::: "memory");                  \
    __builtin_amdgcn_sched_barrier(0);                                      \
    {                                                                       \
      ushort* ap_ = ((I) & 1) ? awB : awA;                                  \
      *(intx4*)ap_ = RA;                                                    \
      *(intx4*)(ap_ + 64 * BK) = RB;                                        \
    }                                                                       \
    asm volatile("s_waitcnt lgkmcnt(0)" ::: "memory");                      \
    __builtin_amdgcn_sched_barrier(0);                                      \
    __builtin_amdgcn_s_barrier();                                           \
    __builtin_amdgcn_sched_barrier(0);                                      \
    COMPUTE((I) & 1);                                                       \
  }

  for (int t = 0; t < S_SZ; ++t) {
    const int p = t & 1;
    const ushort* __restrict__ hin = g_h[p];
    ushort* __restrict__ hout      = g_h[p ^ 1];

    floatx4 acc[4][4];
#pragma unroll
    for (int m = 0; m < 4; ++m)
#pragma unroll
      for (int n = 0; n < 4; ++n) acc[m][n] = {0.f, 0.f, 0.f, 0.f};

    // prologue: A tiles 0..2 to regs, B tile 0 to LDS
    ISSUE_A(0, A0a, A0b);
    ISSUE_A(1, A1a, A1b);
    ISSUE_A(2, A2a, A2b);
    ISSUE_B(0);

    PH(0, 6, A3a, A3b, A0a, A0b);
    PH(1, 6, A0a, A0b, A1a, A1b);
    PH(2, 6, A1a, A1b, A2a, A2b);
    PH(3, 6, A2a, A2b, A3a, A3b);
    PH(4, 6, A3a, A3b, A0a, A0b);
    PH(5, 6, A0a, A0b, A1a, A1b);
    PH(6, 6, A1a, A1b, A2a, A2b);
    PH(7, 6, A2a, A2b, A3a, A3b);
    PH(8, 6, A3a, A3b, A0a, A0b);
    PH(9, 6, A0a, A0b, A1a, A1b);
    PH(10, 6, A1a, A1b, A2a, A2b);
    PH(11, 6, A2a, A2b, A3a, A3b);
    PH(12, 6, A3a, A3b, A0a, A0b);
    PH(13, 4, A0a, A0b, A1a, A1b);
    PH(14, 4, A1a, A1b, A2a, A2b);
    PH(15, 0, A2a, A2b, A3a, A3b);

    // ---------------- epilogue ----------------
    if (t > 0 && tid < BM) {
      float s = bfc[t - 1];
      const float* pr = &g_pp[(t - 1) & 1][brow + tid][0];
#pragma unroll
      for (int j = 0; j < NJT; ++j)
        s += __hip_atomic_load(pr + j, __ATOMIC_RELAXED, __HIP_MEMORY_SCOPE_AGENT);
      xbuf[tid] = s;
      if (jt == 0) out[(size_t)(brow + tid) * S_SZ + (t - 1)] = s;
    }
    __syncthreads();

    const float wfc_l = Wfc[(size_t)t * H_SZ + hcol];  // own-step head weight

#pragma unroll
    for (int m = 0; m < 4; ++m) {
#pragma unroll
      for (int r = 0; r < 4; ++r) {
        const int row_l = wr * 64 + m * 16 + lk * 4 + r;
        const float xv = (t > 0) ? xbuf[row_l] : 0.f;
        float gi = acc[m][0][r] + xv * wih[0] + bb[0];
        float gf = acc[m][1][r] + xv * wih[1] + bb[1];
        float gg = acc[m][2][r] + xv * wih[2] + bb[2];
        float go = acc[m][3][r] + xv * wih[3] + bb[3];
        float cn = fsig(gf) * creg[m][r] + fsig(gi) * ftanh(gg);
        creg[m][r] = cn;
        float hv = fsig(go) * ftanh(cn);
        hout[(size_t)(brow + row_l) * H_SZ + hcol] = f2bf(hv);
        // own-step head partial: pred_t[row] += h_t[row,hcol]*Wfc[t,hcol]
        float pp = hv * wfc_l;
        pp += __shfl_xor(pp, 1);
        pp += __shfl_xor(pp, 2);
        pp += __shfl_xor(pp, 4);
        pp += __shfl_xor(pp, 8);
        if (lr == 0) predp[wc * BM + row_l] = pp;
      }
    }
    __syncthreads();
    if (tid < BM)
      g_pp[p][brow + tid][jt] = predp[tid] + predp[BM + tid] +
                                predp[2 * BM + tid] + predp[3 * BM + tid];

    grp_barrier(grp);
  }

  // final head output for t = S-1 (127 odd -> partials in g_pp[1])
  if (jt == 0 && tid < BM) {
    float s = bfc[S_SZ - 1];
    const float* pr = &g_pp[1][brow + tid][0];
#pragma unroll
    for (int j = 0; j < NJT; ++j)
      s += __hip_atomic_load(pr + j, __ATOMIC_RELAXED, __HIP_MEMORY_SCOPE_AGENT);
    out[(size_t)(brow + tid) * S_SZ + (S_SZ - 1)] = s;
  }
#undef ISSUE_A
#undef ISSUE_B
#undef COMPUTE
#undef PH
}

extern "C" void kernel_launch(void* const* d_in, const int* in_sizes, int n_in,
                              void* d_out, int out_size, void* d_ws, size_t ws_size,
                              hipStream_t stream) {
  const float* hidden = (const float*)d_in[0];
  const float* cell   = (const float*)d_in[1];
  const float* W_ih   = (const float*)d_in[2];
  const float* W_hh   = (const float*)d_in[3];
  const float* b_ih   = (const float*)d_in[4];
  const float* b_hh   = (const float*)d_in[5];
  const float* W_fc   = (const float*)d_in[6];
  const float* b_fc   = (const float*)d_in[7];
  float* out = (float*)d_out;

  prep_wpack<<<2048, 256, 0, stream>>>(W_hh);
  prep_misc<<<16, 256, 0, stream>>>(W_ih, b_ih, b_hh);
  prep_h<<<1024, 256, 0, stream>>>(hidden);

  lstm_persistent<<<NBLK, 512, 0, stream>>>(cell, W_fc, b_fc, out);
}